// Round 1
// baseline (430.873 us; speedup 1.0000x reference)
//
#include <hip/hip_runtime.h>

// Input:  activation (16, 64, 256, 256) fp32, contiguous NCHW.
// Output: same shape/dtype.
// Groups: ch[0,16) b=1 (ReLU), ch[16,40) b=2, ch[40,56) b=3 (edge-clipped),
//         ch[56,64) passthrough copy.
// Block-sum accumulation order matches XLA's sequential row-major reduce
// (init 0, then x[h][w] in row-major order) so mask signs are bit-exact.

static constexpr int W = 256;
static constexpr int HWP = 256 * 256;   // elements per (n,c) plane

// --- ch 0..15 (ReLU) and ch 56..63 (copy): elementwise, float4 ---
// 24 channels x 16 n = 384 planes, 16384 float4 per plane.
__global__ __launch_bounds__(256) void k_elem(const float* __restrict__ in,
                                              float* __restrict__ out) {
    int t = blockIdx.x * 256 + threadIdx.x;        // [0, 384*16384)
    int plane = t >> 14;                           // 16384 float4 / plane
    int off   = t & 16383;
    int n  = plane / 24;
    int cc = plane - n * 24;
    int c  = (cc < 16) ? cc : cc + 40;             // 16..23 -> 56..63
    int idx = (n * 64 + c) * (HWP / 4) + off;      // float4 units
    float4 v = reinterpret_cast<const float4*>(in)[idx];
    if (cc < 16) {
        v.x = (v.x >= 0.f) ? v.x : 0.f;
        v.y = (v.y >= 0.f) ? v.y : 0.f;
        v.z = (v.z >= 0.f) ? v.z : 0.f;
        v.w = (v.w >= 0.f) ? v.w : 0.f;
    }
    reinterpret_cast<float4*>(out)[idx] = v;
}

// --- ch 16..39: 2x2 blocks. Each thread owns TWO adjacent 2x2 blocks
// via two aligned float4 row loads (cols 4q..4q+3, rows 2r..2r+1). ---
// 24 channels x 16 n = 384 planes, 128 blockrows x 64 quad-cols = 8192 thr/plane.
__global__ __launch_bounds__(256) void k_b2(const float* __restrict__ in,
                                            float* __restrict__ out) {
    int t = blockIdx.x * 256 + threadIdx.x;        // [0, 384*8192)
    int plane = t >> 13;
    int off   = t & 8191;
    int brow  = off >> 6;                          // [0,128)
    int q     = off & 63;                          // [0,64)
    int n  = plane / 24;
    int cc = plane - n * 24;
    int base = (n * 64 + cc + 16) * HWP + brow * 2 * W + q * 4;
    float4 a = *reinterpret_cast<const float4*>(in + base);       // row 2r
    float4 b = *reinterpret_cast<const float4*>(in + base + W);   // row 2r+1
    // sequential row-major order: ((x00+x01)+x10)+x11
    float s0 = ((a.x + a.y) + b.x) + b.y;
    float s1 = ((a.z + a.w) + b.z) + b.w;
    if (s0 < 0.f) { a.x = 0.f; a.y = 0.f; b.x = 0.f; b.y = 0.f; }
    if (s1 < 0.f) { a.z = 0.f; a.w = 0.f; b.z = 0.f; b.w = 0.f; }
    *reinterpret_cast<float4*>(out + base)     = a;
    *reinterpret_cast<float4*>(out + base + W) = b;
}

// --- ch 40..55: 3x3 blocks, 86x86 per plane (last row/col clipped to 1). ---
// 16 channels x 16 n = 256 planes x 7396 blocks = 1,893,376 threads.
__global__ __launch_bounds__(256) void k_b3(const float* __restrict__ in,
                                            float* __restrict__ out) {
    int t = blockIdx.x * 256 + threadIdx.x;        // [0, 256*7396)
    int plane = t / 7396;
    int off   = t - plane * 7396;
    int brow  = off / 86;
    int bcol  = off - brow * 86;
    int n = plane >> 4;
    int c = 40 + (plane & 15);
    int r0 = brow * 3;
    int c0 = bcol * 3;
    bool rv = (brow < 85);                         // rows r0+1, r0+2 valid
    bool cv = (bcol < 85);                         // cols c0+1, c0+2 valid
    const float* p = in + (n * 64 + c) * HWP + r0 * W + c0;
    float v00 = p[0];
    float v01 = cv ? p[1] : 0.f;
    float v02 = cv ? p[2] : 0.f;
    float v10 = rv ? p[W + 0] : 0.f;
    float v11 = (rv && cv) ? p[W + 1] : 0.f;
    float v12 = (rv && cv) ? p[W + 2] : 0.f;
    float v20 = rv ? p[2 * W + 0] : 0.f;
    float v21 = (rv && cv) ? p[2 * W + 1] : 0.f;
    float v22 = (rv && cv) ? p[2 * W + 2] : 0.f;
    // sequential row-major accumulation (zeros at padded slots are bit-exact)
    float s = v00;
    s += v01; s += v02;
    s += v10; s += v11; s += v12;
    s += v20; s += v21; s += v22;
    if (s < 0.f) {
        v00 = v01 = v02 = v10 = v11 = v12 = v20 = v21 = v22 = 0.f;
    }
    float* q = out + (n * 64 + c) * HWP + r0 * W + c0;
    q[0] = v00;
    if (cv) { q[1] = v01; q[2] = v02; }
    if (rv) {
        q[W] = v10;
        if (cv) { q[W + 1] = v11; q[W + 2] = v12; }
        q[2 * W] = v20;
        if (cv) { q[2 * W + 1] = v21; q[2 * W + 2] = v22; }
    }
}

extern "C" void kernel_launch(void* const* d_in, const int* in_sizes, int n_in,
                              void* d_out, int out_size, void* d_ws, size_t ws_size,
                              hipStream_t stream) {
    const float* in = (const float*)d_in[0];
    float* out = (float*)d_out;

    // elementwise: 384 planes * 16384 float4 = 6,291,456 threads
    k_elem<<<24576, 256, 0, stream>>>(in, out);
    // b=2: 384 planes * 8192 = 3,145,728 threads
    k_b2<<<12288, 256, 0, stream>>>(in, out);
    // b=3: 256 planes * 7396 = 1,893,376 threads
    k_b3<<<7396, 256, 0, stream>>>(in, out);
}

// Round 2
// 425.597 us; speedup vs baseline: 1.0124x; 1.0124x over previous
//
#include <hip/hip_runtime.h>

// activation (16, 64, 256, 256) fp32 NCHW.
// ch[0,16):  b=1 ReLU          ch[16,40): b=2 block-sign
// ch[40,56): b=3 block-sign (256%3: last row/col block clipped)
// ch[56,64): passthrough copy
// Block sums accumulate sequentially in row-major order (bit-exact vs XLA,
// verified R1 absmax=0.0). Zero-padding slots are skipped (x+0.0 bit-exact).

static constexpr int W   = 256;
static constexpr int HWP = 256 * 256;

// Fused single dispatch: block ranges
//  [0, 24576)          elem/copy: 384 planes * 64 wg   (1 float4/thread)
//  [24576, 36864)      b=2:       384 planes * 32 wg   (2 float4/thread)
//  [36864, 58880)      b=3:       256 planes * 86 row-blocks (LDS staged)
static constexpr int NB_ELEM = 24576;
static constexpr int NB_B2   = 12288;
static constexpr int NB_B3   = 22016;

__global__ __launch_bounds__(256) void fused_blockrelu(const float* __restrict__ in,
                                                       float* __restrict__ out) {
    __shared__ float lds[3 * W];
    __shared__ float msk[86];
    int b   = blockIdx.x;
    int tid = threadIdx.x;

    if (b < NB_ELEM) {
        // --- ch 0..15 ReLU, ch 56..63 copy ---
        int t     = b * 256 + tid;
        int plane = t >> 14;            // 16384 float4 per plane
        int off   = t & 16383;
        int n  = plane / 24;
        int cc = plane - n * 24;
        int c  = (cc < 16) ? cc : cc + 40;
        int idx = (n * 64 + c) * (HWP / 4) + off;
        float4 v = reinterpret_cast<const float4*>(in)[idx];
        if (cc < 16) {
            v.x = (v.x >= 0.f) ? v.x : 0.f;
            v.y = (v.y >= 0.f) ? v.y : 0.f;
            v.z = (v.z >= 0.f) ? v.z : 0.f;
            v.w = (v.w >= 0.f) ? v.w : 0.f;
        }
        reinterpret_cast<float4*>(out)[idx] = v;
        return;
    }
    b -= NB_ELEM;

    if (b < NB_B2) {
        // --- ch 16..39: 2x2 blocks, two blocks per thread via 2 row float4s ---
        int t     = b * 256 + tid;
        int plane = t >> 13;
        int off   = t & 8191;
        int brow  = off >> 6;           // [0,128)
        int q     = off & 63;           // [0,64)
        int n  = plane / 24;
        int cc = plane - n * 24;
        int base = (n * 64 + cc + 16) * HWP + brow * 2 * W + q * 4;
        float4 a = *reinterpret_cast<const float4*>(in + base);
        float4 c4 = *reinterpret_cast<const float4*>(in + base + W);
        float s0 = ((a.x + a.y) + c4.x) + c4.y;   // row-major sequential
        float s1 = ((a.z + a.w) + c4.z) + c4.w;
        if (s0 < 0.f) { a.x = 0.f; a.y = 0.f; c4.x = 0.f; c4.y = 0.f; }
        if (s1 < 0.f) { a.z = 0.f; a.w = 0.f; c4.z = 0.f; c4.w = 0.f; }
        *reinterpret_cast<float4*>(out + base)     = a;
        *reinterpret_cast<float4*>(out + base + W) = c4;
        return;
    }
    b -= NB_B2;

    // --- ch 40..55: 3x3 blocks, LDS-staged, fully float4 global traffic ---
    // One wg per (plane, row-block). rb<85: rows 3rb..3rb+2; rb=85: row 255.
    int rb    = b % 86;
    int plane = b / 86;
    int n = plane >> 4;
    int c = 40 + (plane & 15);
    const float* pin  = in  + (n * 64 + c) * HWP;
    float*       pout = out + (n * 64 + c) * HWP;
    int r0    = rb * 3;
    int nrows = (rb < 85) ? 3 : 1;
    int row = tid >> 6;                 // [0,4)
    int q   = tid & 63;                 // float4 col group

    if (row < nrows) {
        float4 v = *reinterpret_cast<const float4*>(pin + (r0 + row) * W + q * 4);
        *reinterpret_cast<float4*>(&lds[row * W + q * 4]) = v;
    }
    __syncthreads();

    if (tid < 86) {
        int c0    = tid * 3;
        int ncols = (tid < 85) ? 3 : 1;
        float s = 0.f;                  // sequential row-major accumulation
        for (int r = 0; r < nrows; ++r)
            for (int k = 0; k < ncols; ++k)
                s += lds[r * W + c0 + k];
        msk[tid] = (s >= 0.f) ? 1.f : 0.f;
    }
    __syncthreads();

    if (row < nrows) {
        int c0 = q * 4;
        float4 v = *reinterpret_cast<float4*>(&lds[row * W + c0]);
        v.x *= msk[(c0 + 0) / 3];
        v.y *= msk[(c0 + 1) / 3];
        v.z *= msk[(c0 + 2) / 3];
        v.w *= msk[(c0 + 3) / 3];
        *reinterpret_cast<float4*>(pout + (r0 + row) * W + c0) = v;
    }
}

extern "C" void kernel_launch(void* const* d_in, const int* in_sizes, int n_in,
                              void* d_out, int out_size, void* d_ws, size_t ws_size,
                              hipStream_t stream) {
    const float* in = (const float*)d_in[0];
    float* out = (float*)d_out;
    fused_blockrelu<<<NB_ELEM + NB_B2 + NB_B3, 256, 0, stream>>>(in, out);
}